// Round 1
// baseline (134.039 us; speedup 1.0000x reference)
//
#include <hip/hip_runtime.h>
#include <math.h>

constexpr int BLK = 256;
constexpr int PSTRIDE = 256;   // floats per block-partial row (237 used)

__device__ __constant__ int PERMS[24][4] = {
 {0,1,2,3},{0,1,3,2},{0,2,1,3},{0,2,3,1},{0,3,1,2},{0,3,2,1},
 {1,0,2,3},{1,0,3,2},{1,2,0,3},{1,2,3,0},{1,3,0,2},{1,3,2,0},
 {2,0,1,3},{2,0,3,1},{2,1,0,3},{2,1,3,0},{2,3,0,1},{2,3,1,0},
 {3,0,1,2},{3,0,2,1},{3,1,0,2},{3,1,2,0},{3,2,0,1},{3,2,1,0}};

__device__ __forceinline__ float wred(float v) {
#pragma unroll
  for (int off = 32; off; off >>= 1) v += __shfl_down(v, off, 64);
  return v;
}

// Partial layout (floats, per block):
// 0-3 A1, 4 A2, 5-8 Len1, 9 Len2, 10-41 F1[32], 42 F2,
// 43-170 X1[128], 171 X2, 172-235 E1[64], 236 E2
__global__ __launch_bounds__(BLK) void stats_kernel(
    const float* __restrict__ x_focal, const float* __restrict__ p_focal,
    const float* __restrict__ x_neighbor, const float* __restrict__ p_neighbor,
    const float* __restrict__ edge_nei, float* __restrict__ partial, int N) {
  const int tid = threadIdx.x, bid = blockIdx.x, nb = gridDim.x;

  // ---- phase A: per-point angle/length stats ----
  float a1[4] = {0.f,0.f,0.f,0.f}, l1[4] = {0.f,0.f,0.f,0.f};
  float a2 = 0.f, l2 = 0.f;
  const float4* pn4 = (const float4*)p_neighbor;
  for (int n = bid * BLK + tid; n < N; n += nb * BLK) {
    float pf0 = p_focal[n*3+0], pf1 = p_focal[n*3+1], pf2 = p_focal[n*3+2];
    float4 v0 = pn4[n*3+0], v1 = pn4[n*3+1], v2 = pn4[n*3+2];
    float d[4][3];
    d[0][0]=v0.x-pf0; d[0][1]=v0.y-pf1; d[0][2]=v0.z-pf2;
    d[1][0]=v0.w-pf0; d[1][1]=v1.x-pf1; d[1][2]=v1.y-pf2;
    d[2][0]=v1.z-pf0; d[2][1]=v1.w-pf1; d[2][2]=v2.x-pf2;
    d[3][0]=v2.y-pf0; d[3][1]=v2.z-pf1; d[3][2]=v2.w-pf2;
    float len[4];
#pragma unroll
    for (int s = 0; s < 4; ++s)
      len[s] = sqrtf(d[s][0]*d[s][0] + d[s][1]*d[s][1] + d[s][2]*d[s][2]);
#pragma unroll
    for (int s = 0; s < 4; ++s) {
      int sp = (s + 3) & 3;
      float dot = d[sp][0]*d[s][0] + d[sp][1]*d[s][1] + d[sp][2]*d[s][2];
      float a = dot / (fmaxf(len[sp], 1e-8f) * fmaxf(len[s], 1e-8f));
      a1[s] += a; a2 += a * a;
      l1[s] += len[s]; l2 += len[s] * len[s];
    }
  }

  // ---- phase B: x_focal column sums (N x 32 = N x 8 float4) ----
  float4 f1 = {0.f,0.f,0.f,0.f}; float f2 = 0.f;
  {
    const float4* p4 = (const float4*)x_focal;
    int q = tid & 7, rg = tid >> 3;           // 32 rows / block-iter
    for (int r = bid*32 + rg; r < N; r += nb*32) {
      float4 v = p4[r*8 + q];
      f1.x += v.x; f1.y += v.y; f1.z += v.z; f1.w += v.w;
      f2 += v.x*v.x + v.y*v.y + v.z*v.z + v.w*v.w;
    }
  }
  // ---- phase C: x_neighbor column sums (N x 128 = N x 32 float4) ----
  float4 x1 = {0.f,0.f,0.f,0.f}; float x2 = 0.f;
  {
    const float4* p4 = (const float4*)x_neighbor;
    int q = tid & 31, rg = tid >> 5;          // 8 rows / block-iter
    for (int r = bid*8 + rg; r < N; r += nb*8) {
      float4 v = p4[r*32 + q];
      x1.x += v.x; x1.y += v.y; x1.z += v.z; x1.w += v.w;
      x2 += v.x*v.x + v.y*v.y + v.z*v.z + v.w*v.w;
    }
  }
  // ---- phase D: edge_attr_neighbor column sums (N x 64 = N x 16 float4) ----
  float4 e1 = {0.f,0.f,0.f,0.f}; float e2 = 0.f;
  {
    const float4* p4 = (const float4*)edge_nei;
    int q = tid & 15, rg = tid >> 4;          // 16 rows / block-iter
    for (int r = bid*16 + rg; r < N; r += nb*16) {
      float4 v = p4[r*16 + q];
      e1.x += v.x; e1.y += v.y; e1.z += v.z; e1.w += v.w;
      e2 += v.x*v.x + v.y*v.y + v.z*v.z + v.w*v.w;
    }
  }

  // ---- block reduction ----
  __shared__ float4 smq[BLK];
  __shared__ float sms[4][13];
  const int lane = tid & 63, wid = tid >> 6;
  float scal[13] = {a1[0],a1[1],a1[2],a1[3],a2,l1[0],l1[1],l1[2],l1[3],l2,f2,x2,e2};
#pragma unroll
  for (int i = 0; i < 13; ++i) {
    float v = wred(scal[i]);
    if (lane == 0) sms[wid][i] = v;
  }
  float* base = partial + (size_t)bid * PSTRIDE;
  smq[tid] = f1;
  __syncthreads();
  if (tid < 13) {
    const int offs[13] = {0,1,2,3,4,5,6,7,8,9,42,171,236};
    base[offs[tid]] = sms[0][tid] + sms[1][tid] + sms[2][tid] + sms[3][tid];
  }
  if (tid < 8) {
    float4 s = {0.f,0.f,0.f,0.f};
    for (int g = 0; g < 32; ++g) { float4 v = smq[tid + 8*g]; s.x+=v.x; s.y+=v.y; s.z+=v.z; s.w+=v.w; }
    base[10+tid*4+0]=s.x; base[10+tid*4+1]=s.y; base[10+tid*4+2]=s.z; base[10+tid*4+3]=s.w;
  }
  __syncthreads();
  smq[tid] = x1;
  __syncthreads();
  if (tid < 32) {
    float4 s = {0.f,0.f,0.f,0.f};
    for (int g = 0; g < 8; ++g) { float4 v = smq[tid + 32*g]; s.x+=v.x; s.y+=v.y; s.z+=v.z; s.w+=v.w; }
    base[43+tid*4+0]=s.x; base[43+tid*4+1]=s.y; base[43+tid*4+2]=s.z; base[43+tid*4+3]=s.w;
  }
  __syncthreads();
  smq[tid] = e1;
  __syncthreads();
  if (tid < 16) {
    float4 s = {0.f,0.f,0.f,0.f};
    for (int g = 0; g < 16; ++g) { float4 v = smq[tid + 16*g]; s.x+=v.x; s.y+=v.y; s.z+=v.z; s.w+=v.w; }
    base[172+tid*4+0]=s.x; base[172+tid*4+1]=s.y; base[172+tid*4+2]=s.z; base[172+tid*4+3]=s.w;
  }
}

__global__ __launch_bounds__(BLK) void finish_kernel(
    const float* __restrict__ partial, int nb,
    const float* __restrict__ x_center,    // L*32
    const float* __restrict__ x_support,   // L*4*32
    const float* __restrict__ edge_sup,    // L*4*16
    const float* __restrict__ p_support,   // L*4*3
    float* __restrict__ out, int N, int L) {
  __shared__ double tot[240];
  const int tid = threadIdx.x;
  if (tid < 237) {
    double s = 0.0;
    for (int b = 0; b < nb; ++b) s += (double)partial[(size_t)b * PSTRIDE + tid];
    tot[tid] = s;
  }
  __syncthreads();
  if (tid >= L) return;
  const int l = tid;
  const double half_pi = (double)1.5707963705062866;  // float32(pi/2) as in reference
  const double Nd = (double)N;
  const double EPS = 1e-8;

  // support geometry for this l
  double P[4][3], lenp[4];
#pragma unroll
  for (int s = 0; s < 4; ++s) {
#pragma unroll
    for (int c = 0; c < 3; ++c) P[s][c] = (double)p_support[(l*4+s)*3+c];
    lenp[s] = sqrt(P[s][0]*P[s][0] + P[s][1]*P[s][1] + P[s][2]*P[s][2]);
  }
  double cosm[4][4];
#pragma unroll
  for (int u = 0; u < 4; ++u)
#pragma unroll
    for (int v = 0; v < 4; ++v) {
      double dot = P[u][0]*P[v][0] + P[u][1]*P[v][1] + P[u][2]*P[v][2];
      cosm[u][v] = dot / (fmax(lenp[u], EPS) * fmax(lenp[v], EPS));
    }

  const double A1[4] = {tot[0], tot[1], tot[2], tot[3]};
  const double A2 = tot[4];

  // perm selection: argmax atan(1/sum) == first strict min of sum
  double best = 1e300; int bestj = 0;
  for (int j = 0; j < 24; ++j) {
    double dotb = 0.0, b2 = 0.0;
#pragma unroll
    for (int s = 0; s < 4; ++s) {
      int u = PERMS[j][(s+3)&3], v = PERMS[j][s];
      double b = cosm[u][v];
      dotb += b * A1[s];
      b2 += b * b;
    }
    double sum = A2 - 2.0*dotb + Nd*b2;
    if (sum < best) { best = sum; bestj = j; }
  }
  double angle_sc = atan(1.0 / best);
  const int* pj = PERMS[bestj];

  // length score
  double dl = 0.0, lb2 = 0.0;
#pragma unroll
  for (int s = 0; s < 4; ++s) {
    double ls = lenp[pj[s]];
    dl += ls * tot[5+s];
    lb2 += ls * ls;
  }
  double length_sc = atan(1.0 / (tot[9] - 2.0*dl + Nd*lb2));

  // support attr score
  double dx = 0.0, xb2 = 0.0;
  for (int s = 0; s < 4; ++s)
    for (int k = 0; k < 32; ++k) {
      double bx = (double)x_support[(l*4 + pj[s])*32 + k];
      dx += bx * tot[43 + s*32 + k];
      xb2 += bx * bx;
    }
  double supp_sc = atan(1.0 / (tot[171] - 2.0*dx + Nd*xb2));

  // center attr score
  double dc = 0.0, cb2 = 0.0;
  for (int k = 0; k < 32; ++k) {
    double c = (double)x_center[l*32 + k];
    dc += c * tot[10 + k];
    cb2 += c * c;
  }
  double center_sc = atan(1.0 / (tot[42] - 2.0*dc + Nd*cb2));

  // edge attr score
  double de = 0.0, eb2 = 0.0;
  for (int s = 0; s < 4; ++s)
    for (int k = 0; k < 16; ++k) {
      double be = (double)edge_sup[(l*4 + pj[s])*16 + k];
      de += be * tot[172 + s*16 + k];
      eb2 += be * be;
    }
  double edge_sc = atan(1.0 / (tot[236] - 2.0*de + Nd*eb2));

  double t = 0.0;
  double d1 = length_sc - half_pi; t += d1*d1;
  double d2 = angle_sc  - half_pi; t += d2*d2;
  double d3 = supp_sc   - half_pi; t += d3*d3;
  double d4 = center_sc - half_pi; t += d4*d4;
  double d5 = edge_sc   - half_pi; t += d5*d5;
  out[l] = (float)atan(1.0 / t);
}

extern "C" void kernel_launch(void* const* d_in, const int* in_sizes, int n_in,
                              void* d_out, int out_size, void* d_ws, size_t ws_size,
                              hipStream_t stream) {
  const float* x_focal    = (const float*)d_in[0];
  const float* p_focal    = (const float*)d_in[1];
  const float* x_neighbor = (const float*)d_in[2];
  const float* p_neighbor = (const float*)d_in[3];
  const float* edge_nei   = (const float*)d_in[4];
  const float* x_center   = (const float*)d_in[5];
  const float* x_support  = (const float*)d_in[6];
  const float* edge_sup   = (const float*)d_in[7];
  const float* p_support  = (const float*)d_in[8];

  const int N = in_sizes[1] / 3;    // 20000
  const int L = in_sizes[8] / 12;   // 16

  int nb = (int)(ws_size / (PSTRIDE * sizeof(float)));
  if (nb > 120) nb = 120;
  if (nb < 1) nb = 1;

  stats_kernel<<<nb, BLK, 0, stream>>>(x_focal, p_focal, x_neighbor, p_neighbor,
                                       edge_nei, (float*)d_ws, N);
  finish_kernel<<<1, BLK, 0, stream>>>((const float*)d_ws, nb, x_center,
                                       x_support, edge_sup, p_support,
                                       (float*)d_out, N, L);
}

// Round 2
// 104.235 us; speedup vs baseline: 1.2859x; 1.2859x over previous
//
#include <hip/hip_runtime.h>
#include <math.h>

constexpr int BLK = 256;
constexpr int NBLOCKS = 256;

__device__ __constant__ int PERMS[24][4] = {
 {0,1,2,3},{0,1,3,2},{0,2,1,3},{0,2,3,1},{0,3,1,2},{0,3,2,1},
 {1,0,2,3},{1,0,3,2},{1,2,0,3},{1,2,3,0},{1,3,0,2},{1,3,2,0},
 {2,0,1,3},{2,0,3,1},{2,1,0,3},{2,1,3,0},{2,3,0,1},{2,3,1,0},
 {3,0,1,2},{3,0,2,1},{3,1,0,2},{3,1,2,0},{3,2,0,1},{3,2,1,0}};

__device__ __forceinline__ float wred(float v) {
#pragma unroll
  for (int off = 32; off; off >>= 1) v += __shfl_down(v, off, 64);
  return v;
}

// Accumulator layout in d_ws (floats):
// 0-3 A1, 4 A2, 5-8 Len1, 9 Len2, 10-41 F1[32], 42 F2,
// 43-170 X1[128], 171 X2, 172-235 E1[64], 236 E2   (237 used)
__global__ __launch_bounds__(BLK) void stats_kernel(
    const float* __restrict__ x_focal, const float* __restrict__ p_focal,
    const float* __restrict__ x_neighbor, const float* __restrict__ p_neighbor,
    const float* __restrict__ edge_nei, float* __restrict__ gacc, int N) {
  const int tid = threadIdx.x, bid = blockIdx.x, nb = gridDim.x;

  // ---- phase A: per-point angle/length stats ----
  float a1[4] = {0.f,0.f,0.f,0.f}, l1[4] = {0.f,0.f,0.f,0.f};
  float a2 = 0.f, l2 = 0.f;
  const float4* pn4 = (const float4*)p_neighbor;
  for (int n = bid * BLK + tid; n < N; n += nb * BLK) {
    float pf0 = p_focal[n*3+0], pf1 = p_focal[n*3+1], pf2 = p_focal[n*3+2];
    float4 v0 = pn4[n*3+0], v1 = pn4[n*3+1], v2 = pn4[n*3+2];
    float d[4][3];
    d[0][0]=v0.x-pf0; d[0][1]=v0.y-pf1; d[0][2]=v0.z-pf2;
    d[1][0]=v0.w-pf0; d[1][1]=v1.x-pf1; d[1][2]=v1.y-pf2;
    d[2][0]=v1.z-pf0; d[2][1]=v1.w-pf1; d[2][2]=v2.x-pf2;
    d[3][0]=v2.y-pf0; d[3][1]=v2.z-pf1; d[3][2]=v2.w-pf2;
    float len[4];
#pragma unroll
    for (int s = 0; s < 4; ++s)
      len[s] = sqrtf(d[s][0]*d[s][0] + d[s][1]*d[s][1] + d[s][2]*d[s][2]);
#pragma unroll
    for (int s = 0; s < 4; ++s) {
      int sp = (s + 3) & 3;
      float dot = d[sp][0]*d[s][0] + d[sp][1]*d[s][1] + d[sp][2]*d[s][2];
      float a = dot / (fmaxf(len[sp], 1e-8f) * fmaxf(len[s], 1e-8f));
      a1[s] += a; a2 += a * a;
      l1[s] += len[s]; l2 += len[s] * len[s];
    }
  }

  // ---- phase B: x_focal column sums (N x 8 float4) ----
  float4 f1 = {0.f,0.f,0.f,0.f}; float f2 = 0.f;
  {
    const float4* p4 = (const float4*)x_focal;
    int q = tid & 7, rg = tid >> 3;           // 32 rows / block-iter
    for (int r = bid*32 + rg; r < N; r += nb*32) {
      float4 v = p4[r*8 + q];
      f1.x += v.x; f1.y += v.y; f1.z += v.z; f1.w += v.w;
      f2 += v.x*v.x + v.y*v.y + v.z*v.z + v.w*v.w;
    }
  }
  // ---- phase C: x_neighbor column sums (N x 32 float4) ----
  float4 x1 = {0.f,0.f,0.f,0.f}; float x2 = 0.f;
  {
    const float4* p4 = (const float4*)x_neighbor;
    int q = tid & 31, rg = tid >> 5;          // 8 rows / block-iter
    for (int r = bid*8 + rg; r < N; r += nb*8) {
      float4 v = p4[r*32 + q];
      x1.x += v.x; x1.y += v.y; x1.z += v.z; x1.w += v.w;
      x2 += v.x*v.x + v.y*v.y + v.z*v.z + v.w*v.w;
    }
  }
  // ---- phase D: edge_attr_neighbor column sums (N x 16 float4) ----
  float4 e1 = {0.f,0.f,0.f,0.f}; float e2 = 0.f;
  {
    const float4* p4 = (const float4*)edge_nei;
    int q = tid & 15, rg = tid >> 4;          // 16 rows / block-iter
    for (int r = bid*16 + rg; r < N; r += nb*16) {
      float4 v = p4[r*16 + q];
      e1.x += v.x; e1.y += v.y; e1.z += v.z; e1.w += v.w;
      e2 += v.x*v.x + v.y*v.y + v.z*v.z + v.w*v.w;
    }
  }

  // ---- block reduction into LDS, then one atomicAdd per column ----
  __shared__ float outv[240];
  __shared__ float4 smq[BLK];
  __shared__ float sms[4][13];
  const int lane = tid & 63, wid = tid >> 6;
  float scal[13] = {a1[0],a1[1],a1[2],a1[3],a2,l1[0],l1[1],l1[2],l1[3],l2,f2,x2,e2};
#pragma unroll
  for (int i = 0; i < 13; ++i) {
    float v = wred(scal[i]);
    if (lane == 0) sms[wid][i] = v;
  }
  smq[tid] = f1;
  __syncthreads();
  if (tid < 13) {
    const int offs[13] = {0,1,2,3,4,5,6,7,8,9,42,171,236};
    outv[offs[tid]] = sms[0][tid] + sms[1][tid] + sms[2][tid] + sms[3][tid];
  }
  if (tid < 8) {
    float4 s = {0.f,0.f,0.f,0.f};
    for (int g = 0; g < 32; ++g) { float4 v = smq[tid + 8*g]; s.x+=v.x; s.y+=v.y; s.z+=v.z; s.w+=v.w; }
    outv[10+tid*4+0]=s.x; outv[10+tid*4+1]=s.y; outv[10+tid*4+2]=s.z; outv[10+tid*4+3]=s.w;
  }
  __syncthreads();
  smq[tid] = x1;
  __syncthreads();
  if (tid < 32) {
    float4 s = {0.f,0.f,0.f,0.f};
    for (int g = 0; g < 8; ++g) { float4 v = smq[tid + 32*g]; s.x+=v.x; s.y+=v.y; s.z+=v.z; s.w+=v.w; }
    outv[43+tid*4+0]=s.x; outv[43+tid*4+1]=s.y; outv[43+tid*4+2]=s.z; outv[43+tid*4+3]=s.w;
  }
  __syncthreads();
  smq[tid] = e1;
  __syncthreads();
  if (tid < 16) {
    float4 s = {0.f,0.f,0.f,0.f};
    for (int g = 0; g < 16; ++g) { float4 v = smq[tid + 16*g]; s.x+=v.x; s.y+=v.y; s.z+=v.z; s.w+=v.w; }
    outv[172+tid*4+0]=s.x; outv[172+tid*4+1]=s.y; outv[172+tid*4+2]=s.z; outv[172+tid*4+3]=s.w;
  }
  __syncthreads();
  if (tid < 237) atomicAdd(&gacc[tid], outv[tid]);
}

__global__ __launch_bounds__(64) void finish_kernel(
    const float* __restrict__ gacc,
    const float* __restrict__ x_center,    // L*32
    const float* __restrict__ x_support,   // L*4*32
    const float* __restrict__ edge_sup,    // L*4*16
    const float* __restrict__ p_support,   // L*4*3
    float* __restrict__ out, int N, int L) {
  __shared__ double tot[240];
  const int tid = threadIdx.x;
  for (int i = tid; i < 237; i += 64) tot[i] = (double)gacc[i];
  __syncthreads();
  if (tid >= L) return;
  const int l = tid;
  const double half_pi = (double)1.5707963705062866;  // float32(pi/2) as in reference
  const double Nd = (double)N;
  const double EPS = 1e-8;

  // support geometry for this l
  double P[4][3], lenp[4];
#pragma unroll
  for (int s = 0; s < 4; ++s) {
#pragma unroll
    for (int c = 0; c < 3; ++c) P[s][c] = (double)p_support[(l*4+s)*3+c];
    lenp[s] = sqrt(P[s][0]*P[s][0] + P[s][1]*P[s][1] + P[s][2]*P[s][2]);
  }
  double cosm[4][4];
#pragma unroll
  for (int u = 0; u < 4; ++u)
#pragma unroll
    for (int v = 0; v < 4; ++v) {
      double dot = P[u][0]*P[v][0] + P[u][1]*P[v][1] + P[u][2]*P[v][2];
      cosm[u][v] = dot / (fmax(lenp[u], EPS) * fmax(lenp[v], EPS));
    }

  const double A1[4] = {tot[0], tot[1], tot[2], tot[3]};
  const double A2 = tot[4];

  // perm selection: argmax atan(1/sum) == first strict min of expanded sum
  double best = 1e300; int bestj = 0;
  for (int j = 0; j < 24; ++j) {
    double dotb = 0.0, b2 = 0.0;
#pragma unroll
    for (int s = 0; s < 4; ++s) {
      int u = PERMS[j][(s+3)&3], v = PERMS[j][s];
      double b = cosm[u][v];
      dotb += b * A1[s];
      b2 += b * b;
    }
    double sum = A2 - 2.0*dotb + Nd*b2;
    if (sum < best) { best = sum; bestj = j; }
  }
  double angle_sc = atan(1.0 / best);
  const int* pj = PERMS[bestj];

  // length score
  double dl = 0.0, lb2 = 0.0;
#pragma unroll
  for (int s = 0; s < 4; ++s) {
    double ls = lenp[pj[s]];
    dl += ls * tot[5+s];
    lb2 += ls * ls;
  }
  double length_sc = atan(1.0 / (tot[9] - 2.0*dl + Nd*lb2));

  // support attr score
  double dx = 0.0, xb2 = 0.0;
  for (int s = 0; s < 4; ++s)
    for (int k = 0; k < 32; ++k) {
      double bx = (double)x_support[(l*4 + pj[s])*32 + k];
      dx += bx * tot[43 + s*32 + k];
      xb2 += bx * bx;
    }
  double supp_sc = atan(1.0 / (tot[171] - 2.0*dx + Nd*xb2));

  // center attr score
  double dc = 0.0, cb2 = 0.0;
  for (int k = 0; k < 32; ++k) {
    double c = (double)x_center[l*32 + k];
    dc += c * tot[10 + k];
    cb2 += c * c;
  }
  double center_sc = atan(1.0 / (tot[42] - 2.0*dc + Nd*cb2));

  // edge attr score
  double de = 0.0, eb2 = 0.0;
  for (int s = 0; s < 4; ++s)
    for (int k = 0; k < 16; ++k) {
      double be = (double)edge_sup[(l*4 + pj[s])*16 + k];
      de += be * tot[172 + s*16 + k];
      eb2 += be * be;
    }
  double edge_sc = atan(1.0 / (tot[236] - 2.0*de + Nd*eb2));

  double t = 0.0;
  double d1 = length_sc - half_pi; t += d1*d1;
  double d2 = angle_sc  - half_pi; t += d2*d2;
  double d3 = supp_sc   - half_pi; t += d3*d3;
  double d4 = center_sc - half_pi; t += d4*d4;
  double d5 = edge_sc   - half_pi; t += d5*d5;
  out[l] = (float)atan(1.0 / t);
}

extern "C" void kernel_launch(void* const* d_in, const int* in_sizes, int n_in,
                              void* d_out, int out_size, void* d_ws, size_t ws_size,
                              hipStream_t stream) {
  const float* x_focal    = (const float*)d_in[0];
  const float* p_focal    = (const float*)d_in[1];
  const float* x_neighbor = (const float*)d_in[2];
  const float* p_neighbor = (const float*)d_in[3];
  const float* edge_nei   = (const float*)d_in[4];
  const float* x_center   = (const float*)d_in[5];
  const float* x_support  = (const float*)d_in[6];
  const float* edge_sup   = (const float*)d_in[7];
  const float* p_support  = (const float*)d_in[8];

  const int N = in_sizes[1] / 3;    // 20000
  const int L = in_sizes[8] / 12;   // 16

  float* gacc = (float*)d_ws;
  hipMemsetAsync(gacc, 0, 240 * sizeof(float), stream);

  stats_kernel<<<NBLOCKS, BLK, 0, stream>>>(x_focal, p_focal, x_neighbor,
                                            p_neighbor, edge_nei, gacc, N);
  finish_kernel<<<1, 64, 0, stream>>>(gacc, x_center, x_support, edge_sup,
                                      p_support, (float*)d_out, N, L);
}